// Round 2
// baseline (91241.333 us; speedup 1.0000x reference)
//
#include <hip/hip_runtime.h>
#include <math.h>

#define NLATg 181
#define NLONg 360
#define PIXg  65160        // 181*360
#define EMBg  256
#define MHIDg 512
#define PLANEg 8386816     // 181*181*256
#define LDIMg 32761        // 181*181

#define FLAG_GELU 1
#define FLAG_ACC  2

__device__ __forceinline__ float gelu_f(float x) {
    return 0.5f * x * (1.0f + erff(x * 0.70710678118654752440f));
}

// ---------------- init kernels (run every call; graph-capture safe) ----------------

// Orthonormal associated Legendre P[l][m][k], recurrence in fp64, stored fp32.
__global__ __launch_bounds__(256) void init_legendre(float* __restrict__ P) {
    int idx = blockIdx.x * 256 + threadIdx.x;
    if (idx >= 181 * 181) return;
    int m = idx / 181, k = idx % 181;
    double theta = M_PI * (double)k / 180.0;
    double ct = cos(theta), st = sin(theta);
    double pmm = sqrt(1.0 / (4.0 * M_PI));
    for (int j = 1; j <= m; ++j) pmm *= -sqrt((2.0 * j + 1.0) / (2.0 * j)) * st;
    for (int l = 0; l < m; ++l) P[(size_t)l * LDIMg + m * 181 + k] = 0.0f;
    P[(size_t)m * LDIMg + m * 181 + k] = (float)pmm;
    if (m + 1 < 181) {
        double pl1 = sqrt(2.0 * m + 3.0) * ct * pmm;
        P[(size_t)(m + 1) * LDIMg + m * 181 + k] = (float)pl1;
        double pl2 = pmm;
        for (int l = m + 2; l < 181; ++l) {
            double ll = l, mm = m;
            double a = sqrt((4.0 * ll * ll - 1.0) / (ll * ll - mm * mm));
            double b = sqrt(((2.0 * ll + 1.0) * (ll - 1.0 + mm) * (ll - 1.0 - mm)) /
                            ((2.0 * ll - 3.0) * (ll * ll - mm * mm)));
            double p = a * ct * pl1 - b * pl2;
            P[(size_t)l * LDIMg + m * 181 + k] = (float)p;
            pl2 = pl1; pl1 = p;
        }
    }
}

// Etrig[0..]: cos(2pi m n/360); Etrig[65160..]: -sin(...). Dt (iDFT^T 362x360), wqs.
__global__ __launch_bounds__(256) void init_trig(float* __restrict__ Etrig,
                                                 float* __restrict__ Dt, float* __restrict__ wqs) {
    int idx = blockIdx.x * 256 + threadIdx.x;
    if (idx < 181) {
        double theta = M_PI * (double)idx / 180.0;
        wqs[idx] = (float)(2.0 * M_PI * (M_PI / 180.0) * sin(theta) / 360.0);
    }
    if (idx >= 181 * 360) return;
    int m = idx / 360, n = idx % 360;
    int a = (m * n) % 360;           // exact angle reduction
    double ang = M_PI * (double)a / 180.0;
    double c = cos(ang), s = sin(ang);
    Etrig[idx]         = (float)c;
    Etrig[PIXg + idx]  = (float)(-s);
    double cm = (m == 0 || m == 180) ? 1.0 : 2.0;
    Dt[(size_t)m * 360 + n]         = (float)(cm * c);   // cos rows
    Dt[(size_t)(181 + m) * 360 + n] = (float)(-cm * s);  // -sin rows
}

// wt[l][i][o] = W[o][i][l]   (W per-layer: o stride 46336, i stride 181, l stride 1)
__global__ __launch_bounds__(256) void transpose_wspec(const float* __restrict__ W, float* __restrict__ WT) {
    __shared__ float tile[32][33];
    int l0 = blockIdx.x * 32, o0 = blockIdx.y * 32, i = blockIdx.z;
    int c = threadIdx.x & 31, r = threadIdx.x >> 5;
#pragma unroll
    for (int j = 0; j < 4; j++) {
        int row = r + j * 8;
        float v = 0.f;
        if (l0 + c < 181) v = W[(size_t)(o0 + row) * 46336 + i * 181 + (l0 + c)];
        tile[row][c] = v;
    }
    __syncthreads();
#pragma unroll
    for (int j = 0; j < 4; j++) {
        int row = r + j * 8;
        if (l0 + row < 181) WT[(size_t)(l0 + row) * 65536 + i * 256 + (o0 + c)] = tile[c][row];
    }
}

// ---------------- LayerNorm over channel dim (256), per pixel ----------------
__global__ __launch_bounds__(256) void ln_kernel(const float* __restrict__ X, float* __restrict__ Y) {
    int p0 = blockIdx.x * 64;
    int t = threadIdx.x;
    int ps = t & 63, cg = t >> 6;
    int p = p0 + ps;
    bool ok = p < PIXg;
    float sum = 0.f, sumsq = 0.f;
    if (ok) {
        for (int c = cg; c < EMBg; c += 4) {
            float v = X[(size_t)c * PIXg + p];
            sum += v; sumsq += v * v;
        }
    }
    __shared__ float s1[4][64];
    __shared__ float s2[4][64];
    s1[cg][ps] = sum; s2[cg][ps] = sumsq;
    __syncthreads();
    float tot  = s1[0][ps] + s1[1][ps] + s1[2][ps] + s1[3][ps];
    float tot2 = s2[0][ps] + s2[1][ps] + s2[2][ps] + s2[3][ps];
    float mu = tot * (1.0f / 256.0f);
    float var = tot2 * (1.0f / 256.0f) - mu * mu;
    float inv = rsqrtf(var + 1e-6f);
    if (ok) {
        for (int c = cg; c < EMBg; c += 4) {
            size_t offp = (size_t)c * PIXg + p;
            Y[offp] = (X[offp] - mu) * inv;
        }
    }
}

// x1 = gelu(Y + S + bias[c]), float4 over [256][PIX]
__global__ __launch_bounds__(256) void add_bias_gelu(const float* __restrict__ Y, const float* __restrict__ S,
                                                     const float* __restrict__ bsp, float* __restrict__ O) {
    int idx = blockIdx.x * 256 + threadIdx.x;   // float4 index
    int c = idx / 16290;                        // PIX/4 = 16290
    float b = bsp[c];
    float4 y = reinterpret_cast<const float4*>(Y)[idx];
    float4 s = reinterpret_cast<const float4*>(S)[idx];
    float4 o;
    o.x = gelu_f(y.x + s.x + b);
    o.y = gelu_f(y.y + s.y + b);
    o.z = gelu_f(y.z + s.z + b);
    o.w = gelu_f(y.w + s.w + b);
    reinterpret_cast<float4*>(O)[idx] = o;
}

// ---------------- double-buffered strided batched fp32 GEMM ----------------
// C[z][i][j] = sum_k A[z][i][k]*B[z][k][j]; z in [0, Zin*planes); plane stride via *ps.
// epilogue: *zscale[z], +bias[i], +resid (C layout), gelu, +=C
__global__ __launch_bounds__(256, 4) void gemm_f32(
    const float* __restrict__ A, int Ars, int Acs, int Azs, int Aps,
    const float* __restrict__ B, int Brs, int Bcs, int Bzs, int Bps,
    float* __restrict__ C, int Crs, int Ccs, int Czs, int Cps,
    const float* __restrict__ bias, const float* __restrict__ zscale,
    const float* __restrict__ resid,
    int M, int N, int K, int Zin, int flags)
{
    int z = blockIdx.z;
    if (z >= Zin) { z -= Zin; A += Aps; B += Bps; C += Cps; if (resid) resid += Cps; }
    A += (size_t)z * Azs; B += (size_t)z * Bzs; C += (size_t)z * Czs;
    if (resid) resid += (size_t)z * Czs;

    const int bm = blockIdx.y * 128, bn = blockIdx.x * 128;
    const int t = threadIdx.x;
    const int tx = t & 15, ty = t >> 4;

    __shared__ float As[2][16][132];
    __shared__ float Bs[2][16][132];

    const bool ap1 = (Acs == 1);
    const bool bp1 = (Bcs == 1);

    unsigned arow[8]; unsigned arow0 = 0;
    if (ap1) {
#pragma unroll
        for (int i = 0; i < 8; i++) {
            int gr = bm + (t >> 4) + i * 16; if (gr > M - 1) gr = M - 1;
            arow[i] = (unsigned)gr * (unsigned)Ars;
        }
    } else {
        int gr = bm + (t & 127); if (gr > M - 1) gr = M - 1;
        arow0 = (unsigned)gr * (unsigned)Ars;
    }
    unsigned bcol[8]; unsigned bcol0 = 0;
    if (bp1) {
        int gc = bn + (t & 127); if (gc > N - 1) gc = N - 1;
        bcol0 = (unsigned)gc;
    } else {
#pragma unroll
        for (int i = 0; i < 8; i++) {
            int gc = bn + (t >> 4) + i * 16; if (gc > N - 1) gc = N - 1;
            bcol[i] = (unsigned)gc * (unsigned)Bcs;
        }
    }

    float acc[8][8];
#pragma unroll
    for (int i = 0; i < 8; i++)
#pragma unroll
        for (int j = 0; j < 8; j++) acc[i][j] = 0.0f;

    float va[8], vb[8];

    auto loadA = [&](int k0) {
        if (ap1) {
            int gk = k0 + (t & 15); bool kv = gk < K;
#pragma unroll
            for (int i = 0; i < 8; i++) va[i] = kv ? A[arow[i] + (unsigned)gk] : 0.f;
        } else {
#pragma unroll
            for (int i = 0; i < 8; i++) {
                int gk = k0 + (t >> 7) + i * 2;
                va[i] = (gk < K) ? A[arow0 + (unsigned)(gk * Acs)] : 0.f;
            }
        }
    };
    auto loadB = [&](int k0) {
        if (bp1) {
#pragma unroll
            for (int i = 0; i < 8; i++) {
                int gk = k0 + (t >> 7) + i * 2;
                vb[i] = (gk < K) ? B[(unsigned)(gk * Brs) + bcol0] : 0.f;
            }
        } else {
            int gk = k0 + (t & 15); bool kv = gk < K;
#pragma unroll
            for (int i = 0; i < 8; i++) vb[i] = kv ? B[(unsigned)gk + bcol[i]] : 0.f;
        }
    };
    auto storeAB = [&](int buf) {
        if (ap1) {
            int kk = t & 15, r = t >> 4;
#pragma unroll
            for (int i = 0; i < 8; i++) As[buf][kk][r + i * 16] = va[i];
        } else {
            int row = t & 127, kb = t >> 7;
#pragma unroll
            for (int i = 0; i < 8; i++) As[buf][kb + i * 2][row] = va[i];
        }
        if (bp1) {
            int col = t & 127, kb = t >> 7;
#pragma unroll
            for (int i = 0; i < 8; i++) Bs[buf][kb + i * 2][col] = vb[i];
        } else {
            int kk = t & 15, c = t >> 4;
#pragma unroll
            for (int i = 0; i < 8; i++) Bs[buf][kk][c + i * 16] = vb[i];
        }
    };

    const int nk = (K + 15) >> 4;
    loadA(0); loadB(0);
    storeAB(0);
    __syncthreads();
    int cur = 0;
    for (int kt = 0; kt < nk; kt++) {
        if (kt + 1 < nk) { loadA((kt + 1) * 16); loadB((kt + 1) * 16); }
#pragma unroll
        for (int kk = 0; kk < 16; kk++) {
            float4 a0 = *(const float4*)&As[cur][kk][ty * 4];
            float4 a1 = *(const float4*)&As[cur][kk][ty * 4 + 64];
            float4 b0 = *(const float4*)&Bs[cur][kk][tx * 4];
            float4 b1 = *(const float4*)&Bs[cur][kk][tx * 4 + 64];
            float av[8] = {a0.x, a0.y, a0.z, a0.w, a1.x, a1.y, a1.z, a1.w};
            float bv[8] = {b0.x, b0.y, b0.z, b0.w, b1.x, b1.y, b1.z, b1.w};
#pragma unroll
            for (int i = 0; i < 8; i++)
#pragma unroll
                for (int j = 0; j < 8; j++)
                    acc[i][j] = fmaf(av[i], bv[j], acc[i][j]);
        }
        if (kt + 1 < nk) {
            storeAB(cur ^ 1);
            __syncthreads();
            cur ^= 1;
        }
    }

    const float zs = zscale ? zscale[z] : 1.0f;
    const bool fastN = (Ccs == 1) && (bn + 128 <= N);
#pragma unroll
    for (int i = 0; i < 8; i++) {
        int gi = bm + ty * 4 + (i & 3) + ((i >> 2) << 6);
        if (gi >= M) continue;
        float bval = bias ? bias[gi] : 0.0f;
        size_t crow = (size_t)gi * (size_t)Crs;
        if (fastN) {
#pragma unroll
            for (int h = 0; h < 2; h++) {
                int gj = bn + tx * 4 + h * 64;
                size_t off = crow + (size_t)gj;
                float4 v;
                v.x = acc[i][h * 4 + 0] * zs + bval;
                v.y = acc[i][h * 4 + 1] * zs + bval;
                v.z = acc[i][h * 4 + 2] * zs + bval;
                v.w = acc[i][h * 4 + 3] * zs + bval;
                if (resid) { float4 r = *(const float4*)&resid[off];
                             v.x += r.x; v.y += r.y; v.z += r.z; v.w += r.w; }
                if (flags & FLAG_GELU) { v.x = gelu_f(v.x); v.y = gelu_f(v.y);
                                         v.z = gelu_f(v.z); v.w = gelu_f(v.w); }
                if (flags & FLAG_ACC)  { float4 c0 = *(const float4*)&C[off];
                                         v.x += c0.x; v.y += c0.y; v.z += c0.z; v.w += c0.w; }
                *(float4*)&C[off] = v;
            }
        } else {
#pragma unroll
            for (int j = 0; j < 8; j++) {
                int gj = bn + tx * 4 + (j & 3) + ((j >> 2) << 6);
                if (gj >= N) continue;
                size_t off = crow + (size_t)gj * (size_t)Ccs;
                float v = acc[i][j] * zs + bval;
                if (resid) v += resid[off];
                if (flags & FLAG_GELU) v = gelu_f(v);
                if (flags & FLAG_ACC) v += C[off];
                C[off] = v;
            }
        }
    }
}

static inline void launch_gemm(hipStream_t s,
    const float* A, int Ars, int Acs, int Azs, int Aps,
    const float* B, int Brs, int Bcs, int Bzs, int Bps,
    float* C, int Crs, int Ccs, int Czs, int Cps,
    const float* bias, const float* zscale, const float* resid,
    int M, int N, int K, int Zin, int nplanes, int flags)
{
    dim3 grid((N + 127) / 128, (M + 127) / 128, Zin * nplanes);
    hipLaunchKernelGGL(gemm_f32, grid, dim3(256), 0, s,
                       A, Ars, Acs, Azs, Aps, B, Brs, Bcs, Bzs, Bps,
                       C, Crs, Ccs, Czs, Cps, bias, zscale, resid,
                       M, N, K, Zin, flags);
}

extern "C" void kernel_launch(void* const* d_in, const int* in_sizes, int n_in,
                              void* d_out, int out_size, void* d_ws, size_t ws_size,
                              hipStream_t stream)
{
    const float* x      = (const float*)d_in[0];
    const float* w_enc  = (const float*)d_in[1];
    const float* b_enc  = (const float*)d_in[2];
    const float* pos    = (const float*)d_in[3];
    const float* w_spec = (const float*)d_in[4];
    const float* b_spec = (const float*)d_in[5];
    const float* w_is   = (const float*)d_in[6];
    const float* b_is   = (const float*)d_in[7];
    const float* w_f1   = (const float*)d_in[8];
    const float* b_f1   = (const float*)d_in[9];
    const float* w_f2   = (const float*)d_in[10];
    const float* b_f2   = (const float*)d_in[11];
    const float* w_dec  = (const float*)d_in[12];
    const float* b_dec  = (const float*)d_in[13];
    float* out = (float*)d_out;
    float* ws  = (float*)d_ws;

    size_t off = 0;
    auto alloc = [&](size_t n) { size_t o = off; off += (n + 63) & ~(size_t)63; return o; };
    float* P     = ws + alloc((size_t)181 * 181 * 181);
    float* Etrig = ws + alloc((size_t)2 * PIXg);
    float* Dt    = ws + alloc((size_t)362 * 360);
    float* wqs   = ws + alloc(181);
    float* S0    = ws + alloc((size_t)2 * PLANEg);
    float* S1    = ws + alloc((size_t)2 * PLANEg);   // contiguous after S0
    float* hbuf  = ws + alloc((size_t)EMBg * PIXg);
    float* xn    = ws + alloc((size_t)EMBg * PIXg);
    float* tA    = ws + alloc((size_t)EMBg * PIXg);  // wt scratch, then y, then x1
    float* tB    = ws + alloc((size_t)EMBg * PIXg);
    float* hmlp  = S0;   // 512*PIX floats spans S0..S1 (spectral bufs dead by MLP time)

    init_legendre<<<(181 * 181 + 255) / 256, 256, 0, stream>>>(P);
    init_trig<<<(181 * 360 + 255) / 256, 256, 0, stream>>>(Etrig, Dt, wqs);

    // encoder: h = w_enc*x + b_enc + pos_emb
    launch_gemm(stream, w_enc, 26, 1, 0, 0,  x, PIXg, 1, 0, 0,  hbuf, PIXg, 1, 0, 0,
                b_enc, nullptr, pos, EMBg, PIXg, 26, 1, 1, 0);

    for (int L = 0; L < 4; ++L) {
        const float* wsp = w_spec + (size_t)L * EMBg * EMBg * 181;
        const float* bsp = b_spec + (size_t)L * EMBg;
        const float* wis = w_is   + (size_t)L * EMBg * EMBg;
        const float* bis = b_is   + (size_t)L * EMBg;
        const float* wf1 = w_f1   + (size_t)L * MHIDg * EMBg;
        const float* bf1 = b_f1   + (size_t)L * MHIDg;
        const float* wf2 = w_f2   + (size_t)L * EMBg * MHIDg;
        const float* bf2 = b_f2   + (size_t)L * EMBg;

        // wt[l][i][o] = wsp[o][i][l]  (into tA scratch; dead until iDFT output)
        transpose_wspec<<<dim3(6, 8, 256), 256, 0, stream>>>(wsp, tA);

        // xn = LN(h)
        ln_kernel<<<1019, 256, 0, stream>>>(hbuf, xn);

        // DFT (z=k, planes cos/sin): F[pl][k][m][c] = sum_n E[pl][m][n]*xn[c][k*360+n], *wqs[k]
        launch_gemm(stream, Etrig, 360, 1, 0, PIXg,  xn, 1, PIXg, 360, 0,
                    S0, 256, 1, 46336, PLANEg,
                    nullptr, wqs, nullptr, 181, 256, 360, 181, 2, 0);
        // Legendre analysis (z=m): coeff[pl][m][l][c] = sum_k P[l][m][k]*F[pl][k][m][c]
        launch_gemm(stream, P, LDIMg, 1, 181, 0,  S0, 46336, 1, 256, PLANEg,
                    S1, 256, 1, 46336, PLANEg,
                    nullptr, nullptr, nullptr, 181, 256, 181, 181, 2, 0);
        // dhconv (z=l): co[pl][m][l][o] = sum_i coeff[pl][m][l][i]*wt[l][i][o]
        launch_gemm(stream, S1, 46336, 1, 256, PLANEg,  tA, 256, 1, 65536, 0,
                    S0, 46336, 1, 256, PLANEg,
                    nullptr, nullptr, nullptr, 181, 256, 256, 181, 2, 0);
        // Legendre synthesis (z=m): Fo[pl][m][k][c] = sum_l P[l][m][k]*co[pl][m][l][c]
        launch_gemm(stream, P, 1, LDIMg, 181, 0,  S0, 256, 1, 46336, PLANEg,
                    S1, 256, 1, 46336, PLANEg,
                    nullptr, nullptr, nullptr, 181, 256, 181, 181, 2, 0);
        // iDFT (z=k): y[c][k*360+n] = sum_m Fo_re[m][k][c]*Dtc[m][n] (+ im part)
        launch_gemm(stream, S1, 1, 46336, 256, 0,  Dt, 360, 1, 0, 0,
                    tA, PIXg, 1, 360, 0,
                    nullptr, nullptr, nullptr, 256, 360, 181, 181, 1, 0);
        launch_gemm(stream, S1 + PLANEg, 1, 46336, 256, 0,  Dt + (size_t)181 * 360, 360, 1, 0, 0,
                    tA, PIXg, 1, 360, 0,
                    nullptr, nullptr, nullptr, 256, 360, 181, 181, 1, FLAG_ACC);
        // inner skip: S = wis*xn + bis -> tB
        launch_gemm(stream, wis, 256, 1, 0, 0,  xn, PIXg, 1, 0, 0,  tB, PIXg, 1, 0, 0,
                    bis, nullptr, nullptr, 256, PIXg, 256, 1, 1, 0);
        // x1 = gelu(y + b_spec + S) -> tA
        add_bias_gelu<<<16290, 256, 0, stream>>>(tA, tB, bsp, tA);
        // x2 = LN(x1) -> tB
        ln_kernel<<<1019, 256, 0, stream>>>(tA, tB);
        // MLP fc1: hmlp = gelu(wf1*x2 + bf1)
        launch_gemm(stream, wf1, 256, 1, 0, 0,  tB, PIXg, 1, 0, 0,  hmlp, PIXg, 1, 0, 0,
                    bf1, nullptr, nullptr, MHIDg, PIXg, 256, 1, 1, FLAG_GELU);
        // MLP fc2 + residual xn -> h
        launch_gemm(stream, wf2, 512, 1, 0, 0,  hmlp, PIXg, 1, 0, 0,  hbuf, PIXg, 1, 0, 0,
                    bf2, nullptr, xn, EMBg, PIXg, 512, 1, 1, 0);
    }

    // decoder: out = w_dec[:, :256]*h + w_dec[:, 256:]*x + b_dec
    launch_gemm(stream, w_dec, 282, 1, 0, 0,  hbuf, PIXg, 1, 0, 0,  out, PIXg, 1, 0, 0,
                b_dec, nullptr, nullptr, 26, PIXg, 256, 1, 1, 0);
    launch_gemm(stream, w_dec + 256, 282, 1, 0, 0,  x, PIXg, 1, 0, 0,  out, PIXg, 1, 0, 0,
                nullptr, nullptr, nullptr, 26, PIXg, 26, 1, 1, FLAG_ACC);
}

// Round 3
// 45334.274 us; speedup vs baseline: 2.0126x; 2.0126x over previous
//
#include <hip/hip_runtime.h>
#include <math.h>

#define NLATg 181
#define NLONg 360
#define PIXg  65160        // 181*360
#define EMBg  256
#define MHIDg 512
#define PLANEg 8386816     // 181*181*256
#define LDIMg 32761        // 181*181

#define FLAG_GELU 1
#define FLAG_ACC  2

__device__ __forceinline__ float gelu_f(float x) {
    return 0.5f * x * (1.0f + erff(x * 0.70710678118654752440f));
}

// ---------------- init kernels (run every call; graph-capture safe) ----------------

// Orthonormal associated Legendre P[l][m][k], recurrence in fp64, stored fp32.
__global__ __launch_bounds__(256) void init_legendre(float* __restrict__ P) {
    int idx = blockIdx.x * 256 + threadIdx.x;
    if (idx >= 181 * 181) return;
    int m = idx / 181, k = idx % 181;
    double theta = M_PI * (double)k / 180.0;
    double ct = cos(theta), st = sin(theta);
    double pmm = sqrt(1.0 / (4.0 * M_PI));
    for (int j = 1; j <= m; ++j) pmm *= -sqrt((2.0 * j + 1.0) / (2.0 * j)) * st;
    for (int l = 0; l < m; ++l) P[(size_t)l * LDIMg + m * 181 + k] = 0.0f;
    P[(size_t)m * LDIMg + m * 181 + k] = (float)pmm;
    if (m + 1 < 181) {
        double pl1 = sqrt(2.0 * m + 3.0) * ct * pmm;
        P[(size_t)(m + 1) * LDIMg + m * 181 + k] = (float)pl1;
        double pl2 = pmm;
        for (int l = m + 2; l < 181; ++l) {
            double ll = l, mm = m;
            double a = sqrt((4.0 * ll * ll - 1.0) / (ll * ll - mm * mm));
            double b = sqrt(((2.0 * ll + 1.0) * (ll - 1.0 + mm) * (ll - 1.0 - mm)) /
                            ((2.0 * ll - 3.0) * (ll * ll - mm * mm)));
            double p = a * ct * pl1 - b * pl2;
            P[(size_t)l * LDIMg + m * 181 + k] = (float)p;
            pl2 = pl1; pl1 = p;
        }
    }
}

// Etrig[0..]: cos(2pi m n/360); Etrig[65160..]: -sin(...). Dt (iDFT^T 362x360), wqs.
__global__ __launch_bounds__(256) void init_trig(float* __restrict__ Etrig,
                                                 float* __restrict__ Dt, float* __restrict__ wqs) {
    int idx = blockIdx.x * 256 + threadIdx.x;
    if (idx < 181) {
        double theta = M_PI * (double)idx / 180.0;
        wqs[idx] = (float)(2.0 * M_PI * (M_PI / 180.0) * sin(theta) / 360.0);
    }
    if (idx >= 181 * 360) return;
    int m = idx / 360, n = idx % 360;
    int a = (m * n) % 360;           // exact angle reduction
    double ang = M_PI * (double)a / 180.0;
    double c = cos(ang), s = sin(ang);
    Etrig[idx]         = (float)c;
    Etrig[PIXg + idx]  = (float)(-s);
    double cm = (m == 0 || m == 180) ? 1.0 : 2.0;
    Dt[(size_t)m * 360 + n]         = (float)(cm * c);   // cos rows
    Dt[(size_t)(181 + m) * 360 + n] = (float)(-cm * s);  // -sin rows
}

// wt[l][i][o] = W[o][i][l]   (W per-layer: o stride 46336, i stride 181, l stride 1)
__global__ __launch_bounds__(256) void transpose_wspec(const float* __restrict__ W, float* __restrict__ WT) {
    __shared__ float tile[32][33];
    int l0 = blockIdx.x * 32, o0 = blockIdx.y * 32, i = blockIdx.z;
    int c = threadIdx.x & 31, r = threadIdx.x >> 5;
#pragma unroll
    for (int j = 0; j < 4; j++) {
        int row = r + j * 8;
        float v = 0.f;
        if (l0 + c < 181) v = W[(size_t)(o0 + row) * 46336 + i * 181 + (l0 + c)];
        tile[row][c] = v;
    }
    __syncthreads();
#pragma unroll
    for (int j = 0; j < 4; j++) {
        int row = r + j * 8;
        if (l0 + row < 181) WT[(size_t)(l0 + row) * 65536 + i * 256 + (o0 + c)] = tile[c][row];
    }
}

// ---------------- LayerNorm over channel dim (256), per pixel ----------------
__global__ __launch_bounds__(256) void ln_kernel(const float* __restrict__ X, float* __restrict__ Y) {
    int p0 = blockIdx.x * 64;
    int t = threadIdx.x;
    int ps = t & 63, cg = t >> 6;
    int p = p0 + ps;
    bool ok = p < PIXg;
    float sum = 0.f, sumsq = 0.f;
    if (ok) {
        for (int c = cg; c < EMBg; c += 4) {
            float v = X[(size_t)c * PIXg + p];
            sum += v; sumsq += v * v;
        }
    }
    __shared__ float s1[4][64];
    __shared__ float s2[4][64];
    s1[cg][ps] = sum; s2[cg][ps] = sumsq;
    __syncthreads();
    float tot  = s1[0][ps] + s1[1][ps] + s1[2][ps] + s1[3][ps];
    float tot2 = s2[0][ps] + s2[1][ps] + s2[2][ps] + s2[3][ps];
    float mu = tot * (1.0f / 256.0f);
    float var = tot2 * (1.0f / 256.0f) - mu * mu;
    float inv = rsqrtf(var + 1e-6f);
    if (ok) {
        for (int c = cg; c < EMBg; c += 4) {
            size_t offp = (size_t)c * PIXg + p;
            Y[offp] = (X[offp] - mu) * inv;
        }
    }
}

// x1 = gelu(Y + S + bias[c]), float4 over [256][PIX]
__global__ __launch_bounds__(256) void add_bias_gelu(const float* __restrict__ Y, const float* __restrict__ S,
                                                     const float* __restrict__ bsp, float* __restrict__ O) {
    int idx = blockIdx.x * 256 + threadIdx.x;   // float4 index
    int c = idx / 16290;                        // PIX/4 = 16290
    float b = bsp[c];
    float4 y = reinterpret_cast<const float4*>(Y)[idx];
    float4 s = reinterpret_cast<const float4*>(S)[idx];
    float4 o;
    o.x = gelu_f(y.x + s.x + b);
    o.y = gelu_f(y.y + s.y + b);
    o.z = gelu_f(y.z + s.z + b);
    o.w = gelu_f(y.w + s.w + b);
    reinterpret_cast<float4*>(O)[idx] = o;
}

// ---------------- double-buffered strided batched fp32 GEMM ----------------
// C[z][i][j] = sum_k A[z][i][k]*B[z][k][j]; z in [0, Zin*planes); plane stride via *ps.
// epilogue: *zscale[z], +bias[i], +resid (C layout), gelu, +=C
// NOTE: __launch_bounds__(256, 2) — (256,4) forced a 64-VGPR allocation that
// spilled the 8x8 accumulator to scratch (round-2: 8 GB/dispatch spill traffic).
__global__ __launch_bounds__(256, 2) void gemm_f32(
    const float* __restrict__ A, int Ars, int Acs, int Azs, int Aps,
    const float* __restrict__ B, int Brs, int Bcs, int Bzs, int Bps,
    float* __restrict__ C, int Crs, int Ccs, int Czs, int Cps,
    const float* __restrict__ bias, const float* __restrict__ zscale,
    const float* __restrict__ resid,
    int M, int N, int K, int Zin, int flags)
{
    int z = blockIdx.z;
    if (z >= Zin) { z -= Zin; A += Aps; B += Bps; C += Cps; if (resid) resid += Cps; }
    A += (size_t)z * Azs; B += (size_t)z * Bzs; C += (size_t)z * Czs;
    if (resid) resid += (size_t)z * Czs;

    const int bm = blockIdx.y * 128, bn = blockIdx.x * 128;
    const int t = threadIdx.x;
    const int tx = t & 15, ty = t >> 4;

    __shared__ float As[2][16][132];
    __shared__ float Bs[2][16][132];

    const bool ap1 = (Acs == 1);
    const bool bp1 = (Bcs == 1);

    unsigned arow[8]; unsigned arow0 = 0;
    if (ap1) {
#pragma unroll
        for (int i = 0; i < 8; i++) {
            int gr = bm + (t >> 4) + i * 16; if (gr > M - 1) gr = M - 1;
            arow[i] = (unsigned)gr * (unsigned)Ars;
        }
    } else {
        int gr = bm + (t & 127); if (gr > M - 1) gr = M - 1;
        arow0 = (unsigned)gr * (unsigned)Ars;
    }
    unsigned bcol[8]; unsigned bcol0 = 0;
    if (bp1) {
        int gc = bn + (t & 127); if (gc > N - 1) gc = N - 1;
        bcol0 = (unsigned)gc;
    } else {
#pragma unroll
        for (int i = 0; i < 8; i++) {
            int gc = bn + (t >> 4) + i * 16; if (gc > N - 1) gc = N - 1;
            bcol[i] = (unsigned)gc * (unsigned)Bcs;
        }
    }

    float acc[8][8];
#pragma unroll
    for (int i = 0; i < 8; i++)
#pragma unroll
        for (int j = 0; j < 8; j++) acc[i][j] = 0.0f;

    float va[8], vb[8];

    auto loadA = [&](int k0) {
        if (ap1) {
            int gk = k0 + (t & 15); bool kv = gk < K;
#pragma unroll
            for (int i = 0; i < 8; i++) va[i] = kv ? A[arow[i] + (unsigned)gk] : 0.f;
        } else {
#pragma unroll
            for (int i = 0; i < 8; i++) {
                int gk = k0 + (t >> 7) + i * 2;
                va[i] = (gk < K) ? A[arow0 + (unsigned)(gk * Acs)] : 0.f;
            }
        }
    };
    auto loadB = [&](int k0) {
        if (bp1) {
#pragma unroll
            for (int i = 0; i < 8; i++) {
                int gk = k0 + (t >> 7) + i * 2;
                vb[i] = (gk < K) ? B[(unsigned)(gk * Brs) + bcol0] : 0.f;
            }
        } else {
            int gk = k0 + (t & 15); bool kv = gk < K;
#pragma unroll
            for (int i = 0; i < 8; i++) vb[i] = kv ? B[(unsigned)gk + bcol[i]] : 0.f;
        }
    };
    auto storeAB = [&](int buf) {
        if (ap1) {
            int kk = t & 15, r = t >> 4;
#pragma unroll
            for (int i = 0; i < 8; i++) As[buf][kk][r + i * 16] = va[i];
        } else {
            int row = t & 127, kb = t >> 7;
#pragma unroll
            for (int i = 0; i < 8; i++) As[buf][kb + i * 2][row] = va[i];
        }
        if (bp1) {
            int col = t & 127, kb = t >> 7;
#pragma unroll
            for (int i = 0; i < 8; i++) Bs[buf][kb + i * 2][col] = vb[i];
        } else {
            int kk = t & 15, c = t >> 4;
#pragma unroll
            for (int i = 0; i < 8; i++) Bs[buf][kk][c + i * 16] = vb[i];
        }
    };

    const int nk = (K + 15) >> 4;
    loadA(0); loadB(0);
    storeAB(0);
    __syncthreads();
    int cur = 0;
    for (int kt = 0; kt < nk; kt++) {
        if (kt + 1 < nk) { loadA((kt + 1) * 16); loadB((kt + 1) * 16); }
#pragma unroll
        for (int kk = 0; kk < 16; kk++) {
            float4 a0 = *(const float4*)&As[cur][kk][ty * 4];
            float4 a1 = *(const float4*)&As[cur][kk][ty * 4 + 64];
            float4 b0 = *(const float4*)&Bs[cur][kk][tx * 4];
            float4 b1 = *(const float4*)&Bs[cur][kk][tx * 4 + 64];
            float av[8] = {a0.x, a0.y, a0.z, a0.w, a1.x, a1.y, a1.z, a1.w};
            float bv[8] = {b0.x, b0.y, b0.z, b0.w, b1.x, b1.y, b1.z, b1.w};
#pragma unroll
            for (int i = 0; i < 8; i++)
#pragma unroll
                for (int j = 0; j < 8; j++)
                    acc[i][j] = fmaf(av[i], bv[j], acc[i][j]);
        }
        if (kt + 1 < nk) {
            storeAB(cur ^ 1);
            __syncthreads();
            cur ^= 1;
        }
    }

    const float zs = zscale ? zscale[z] : 1.0f;
    const bool fastN = (Ccs == 1) && (bn + 128 <= N);
#pragma unroll
    for (int i = 0; i < 8; i++) {
        int gi = bm + ty * 4 + (i & 3) + ((i >> 2) << 6);
        if (gi >= M) continue;
        float bval = bias ? bias[gi] : 0.0f;
        size_t crow = (size_t)gi * (size_t)Crs;
        if (fastN) {
#pragma unroll
            for (int h = 0; h < 2; h++) {
                int gj = bn + tx * 4 + h * 64;
                size_t off = crow + (size_t)gj;
                float4 v;
                v.x = acc[i][h * 4 + 0] * zs + bval;
                v.y = acc[i][h * 4 + 1] * zs + bval;
                v.z = acc[i][h * 4 + 2] * zs + bval;
                v.w = acc[i][h * 4 + 3] * zs + bval;
                if (resid) { float4 r = *(const float4*)&resid[off];
                             v.x += r.x; v.y += r.y; v.z += r.z; v.w += r.w; }
                if (flags & FLAG_GELU) { v.x = gelu_f(v.x); v.y = gelu_f(v.y);
                                         v.z = gelu_f(v.z); v.w = gelu_f(v.w); }
                if (flags & FLAG_ACC)  { float4 c0 = *(const float4*)&C[off];
                                         v.x += c0.x; v.y += c0.y; v.z += c0.z; v.w += c0.w; }
                *(float4*)&C[off] = v;
            }
        } else {
#pragma unroll
            for (int j = 0; j < 8; j++) {
                int gj = bn + tx * 4 + (j & 3) + ((j >> 2) << 6);
                if (gj >= N) continue;
                size_t off = crow + (size_t)gj * (size_t)Ccs;
                float v = acc[i][j] * zs + bval;
                if (resid) v += resid[off];
                if (flags & FLAG_GELU) v = gelu_f(v);
                if (flags & FLAG_ACC) v += C[off];
                C[off] = v;
            }
        }
    }
}

static inline void launch_gemm(hipStream_t s,
    const float* A, int Ars, int Acs, int Azs, int Aps,
    const float* B, int Brs, int Bcs, int Bzs, int Bps,
    float* C, int Crs, int Ccs, int Czs, int Cps,
    const float* bias, const float* zscale, const float* resid,
    int M, int N, int K, int Zin, int nplanes, int flags)
{
    dim3 grid((N + 127) / 128, (M + 127) / 128, Zin * nplanes);
    hipLaunchKernelGGL(gemm_f32, grid, dim3(256), 0, s,
                       A, Ars, Acs, Azs, Aps, B, Brs, Bcs, Bzs, Bps,
                       C, Crs, Ccs, Czs, Cps, bias, zscale, resid,
                       M, N, K, Zin, flags);
}

extern "C" void kernel_launch(void* const* d_in, const int* in_sizes, int n_in,
                              void* d_out, int out_size, void* d_ws, size_t ws_size,
                              hipStream_t stream)
{
    const float* x      = (const float*)d_in[0];
    const float* w_enc  = (const float*)d_in[1];
    const float* b_enc  = (const float*)d_in[2];
    const float* pos    = (const float*)d_in[3];
    const float* w_spec = (const float*)d_in[4];
    const float* b_spec = (const float*)d_in[5];
    const float* w_is   = (const float*)d_in[6];
    const float* b_is   = (const float*)d_in[7];
    const float* w_f1   = (const float*)d_in[8];
    const float* b_f1   = (const float*)d_in[9];
    const float* w_f2   = (const float*)d_in[10];
    const float* b_f2   = (const float*)d_in[11];
    const float* w_dec  = (const float*)d_in[12];
    const float* b_dec  = (const float*)d_in[13];
    float* out = (float*)d_out;
    float* ws  = (float*)d_ws;

    size_t off = 0;
    auto alloc = [&](size_t n) { size_t o = off; off += (n + 63) & ~(size_t)63; return o; };
    float* P     = ws + alloc((size_t)181 * 181 * 181);
    float* Etrig = ws + alloc((size_t)2 * PIXg);
    float* Dt    = ws + alloc((size_t)362 * 360);
    float* wqs   = ws + alloc(181);
    float* S0    = ws + alloc((size_t)2 * PLANEg);
    float* S1    = ws + alloc((size_t)2 * PLANEg);   // contiguous after S0
    float* hbuf  = ws + alloc((size_t)EMBg * PIXg);
    float* xn    = ws + alloc((size_t)EMBg * PIXg);
    float* tA    = ws + alloc((size_t)EMBg * PIXg);  // wt scratch, then y, then x1
    float* tB    = ws + alloc((size_t)EMBg * PIXg);
    float* hmlp  = S0;   // 512*PIX floats spans S0..S1 (spectral bufs dead by MLP time)

    init_legendre<<<(181 * 181 + 255) / 256, 256, 0, stream>>>(P);
    init_trig<<<(181 * 360 + 255) / 256, 256, 0, stream>>>(Etrig, Dt, wqs);

    // encoder: h = w_enc*x + b_enc + pos_emb
    launch_gemm(stream, w_enc, 26, 1, 0, 0,  x, PIXg, 1, 0, 0,  hbuf, PIXg, 1, 0, 0,
                b_enc, nullptr, pos, EMBg, PIXg, 26, 1, 1, 0);

    for (int L = 0; L < 4; ++L) {
        const float* wsp = w_spec + (size_t)L * EMBg * EMBg * 181;
        const float* bsp = b_spec + (size_t)L * EMBg;
        const float* wis = w_is   + (size_t)L * EMBg * EMBg;
        const float* bis = b_is   + (size_t)L * EMBg;
        const float* wf1 = w_f1   + (size_t)L * MHIDg * EMBg;
        const float* bf1 = b_f1   + (size_t)L * MHIDg;
        const float* wf2 = w_f2   + (size_t)L * EMBg * MHIDg;
        const float* bf2 = b_f2   + (size_t)L * EMBg;

        // wt[l][i][o] = wsp[o][i][l]  (into tA scratch; dead until iDFT output)
        transpose_wspec<<<dim3(6, 8, 256), 256, 0, stream>>>(wsp, tA);

        // xn = LN(h)
        ln_kernel<<<1019, 256, 0, stream>>>(hbuf, xn);

        // DFT (z=k, planes cos/sin): F[pl][k][m][c] = sum_n E[pl][m][n]*xn[c][k*360+n], *wqs[k]
        launch_gemm(stream, Etrig, 360, 1, 0, PIXg,  xn, 1, PIXg, 360, 0,
                    S0, 256, 1, 46336, PLANEg,
                    nullptr, wqs, nullptr, 181, 256, 360, 181, 2, 0);
        // Legendre analysis (z=m): coeff[pl][m][l][c] = sum_k P[l][m][k]*F[pl][k][m][c]
        launch_gemm(stream, P, LDIMg, 1, 181, 0,  S0, 46336, 1, 256, PLANEg,
                    S1, 256, 1, 46336, PLANEg,
                    nullptr, nullptr, nullptr, 181, 256, 181, 181, 2, 0);
        // dhconv (z=l): co[pl][m][l][o] = sum_i coeff[pl][m][l][i]*wt[l][i][o]
        launch_gemm(stream, S1, 46336, 1, 256, PLANEg,  tA, 256, 1, 65536, 0,
                    S0, 46336, 1, 256, PLANEg,
                    nullptr, nullptr, nullptr, 181, 256, 256, 181, 2, 0);
        // Legendre synthesis (z=m): Fo[pl][m][k][c] = sum_l P[l][m][k]*co[pl][m][l][c]
        launch_gemm(stream, P, 1, LDIMg, 181, 0,  S0, 256, 1, 46336, PLANEg,
                    S1, 256, 1, 46336, PLANEg,
                    nullptr, nullptr, nullptr, 181, 256, 181, 181, 2, 0);
        // iDFT (z=k): y[c][k*360+n] = sum_m Fo_re[m][k][c]*Dtc[m][n] (+ im part)
        launch_gemm(stream, S1, 1, 46336, 256, 0,  Dt, 360, 1, 0, 0,
                    tA, PIXg, 1, 360, 0,
                    nullptr, nullptr, nullptr, 256, 360, 181, 181, 1, 0);
        launch_gemm(stream, S1 + PLANEg, 1, 46336, 256, 0,  Dt + (size_t)181 * 360, 360, 1, 0, 0,
                    tA, PIXg, 1, 360, 0,
                    nullptr, nullptr, nullptr, 256, 360, 181, 181, 1, FLAG_ACC);
        // inner skip: S = wis*xn + bis -> tB
        launch_gemm(stream, wis, 256, 1, 0, 0,  xn, PIXg, 1, 0, 0,  tB, PIXg, 1, 0, 0,
                    bis, nullptr, nullptr, 256, PIXg, 256, 1, 1, 0);
        // x1 = gelu(y + b_spec + S) -> tA
        add_bias_gelu<<<16290, 256, 0, stream>>>(tA, tB, bsp, tA);
        // x2 = LN(x1) -> tB
        ln_kernel<<<1019, 256, 0, stream>>>(tA, tB);
        // MLP fc1: hmlp = gelu(wf1*x2 + bf1)
        launch_gemm(stream, wf1, 256, 1, 0, 0,  tB, PIXg, 1, 0, 0,  hmlp, PIXg, 1, 0, 0,
                    bf1, nullptr, nullptr, MHIDg, PIXg, 256, 1, 1, FLAG_GELU);
        // MLP fc2 + residual xn -> h
        launch_gemm(stream, wf2, 512, 1, 0, 0,  hmlp, PIXg, 1, 0, 0,  hbuf, PIXg, 1, 0, 0,
                    bf2, nullptr, xn, EMBg, PIXg, 512, 1, 1, 0);
    }

    // decoder: out = w_dec[:, :256]*h + w_dec[:, 256:]*x + b_dec
    launch_gemm(stream, w_dec, 282, 1, 0, 0,  hbuf, PIXg, 1, 0, 0,  out, PIXg, 1, 0, 0,
                b_dec, nullptr, nullptr, 26, PIXg, 256, 1, 1, 0);
    launch_gemm(stream, w_dec + 256, 282, 1, 0, 0,  x, PIXg, 1, 0, 0,  out, PIXg, 1, 0, 0,
                nullptr, nullptr, nullptr, 26, PIXg, 26, 1, 1, FLAG_ACC);
}

// Round 4
// 10698.486 us; speedup vs baseline: 8.5284x; 4.2374x over previous
//
#include <hip/hip_runtime.h>
#include <math.h>

#define NLATg 181
#define NLONg 360
#define PIXg  65160        // 181*360
#define EMBg  256
#define MHIDg 512
#define PLANEg 8386816     // 181*181*256
#define LDIMg 32761        // 181*181

#define FLAG_GELU 1
#define FLAG_ACC  2

__device__ __forceinline__ float gelu_f(float x) {
    return 0.5f * x * (1.0f + erff(x * 0.70710678118654752440f));
}

// ---------------- init kernels (run every call; graph-capture safe) ----------------

// Orthonormal associated Legendre P[l][m][k], recurrence in fp64, stored fp32.
__global__ __launch_bounds__(256) void init_legendre(float* __restrict__ P) {
    int idx = blockIdx.x * 256 + threadIdx.x;
    if (idx >= 181 * 181) return;
    int m = idx / 181, k = idx % 181;
    double theta = M_PI * (double)k / 180.0;
    double ct = cos(theta), st = sin(theta);
    double pmm = sqrt(1.0 / (4.0 * M_PI));
    for (int j = 1; j <= m; ++j) pmm *= -sqrt((2.0 * j + 1.0) / (2.0 * j)) * st;
    for (int l = 0; l < m; ++l) P[(size_t)l * LDIMg + m * 181 + k] = 0.0f;
    P[(size_t)m * LDIMg + m * 181 + k] = (float)pmm;
    if (m + 1 < 181) {
        double pl1 = sqrt(2.0 * m + 3.0) * ct * pmm;
        P[(size_t)(m + 1) * LDIMg + m * 181 + k] = (float)pl1;
        double pl2 = pmm;
        for (int l = m + 2; l < 181; ++l) {
            double ll = l, mm = m;
            double a = sqrt((4.0 * ll * ll - 1.0) / (ll * ll - mm * mm));
            double b = sqrt(((2.0 * ll + 1.0) * (ll - 1.0 + mm) * (ll - 1.0 - mm)) /
                            ((2.0 * ll - 3.0) * (ll * ll - mm * mm)));
            double p = a * ct * pl1 - b * pl2;
            P[(size_t)l * LDIMg + m * 181 + k] = (float)p;
            pl2 = pl1; pl1 = p;
        }
    }
}

// Etrig[0..]: cos(2pi m n/360); Etrig[65160..]: -sin(...). Dt (iDFT^T 362x360), wqs.
__global__ __launch_bounds__(256) void init_trig(float* __restrict__ Etrig,
                                                 float* __restrict__ Dt, float* __restrict__ wqs) {
    int idx = blockIdx.x * 256 + threadIdx.x;
    if (idx < 181) {
        double theta = M_PI * (double)idx / 180.0;
        wqs[idx] = (float)(2.0 * M_PI * (M_PI / 180.0) * sin(theta) / 360.0);
    }
    if (idx >= 181 * 360) return;
    int m = idx / 360, n = idx % 360;
    int a = (m * n) % 360;           // exact angle reduction
    double ang = M_PI * (double)a / 180.0;
    double c = cos(ang), s = sin(ang);
    Etrig[idx]         = (float)c;
    Etrig[PIXg + idx]  = (float)(-s);
    double cm = (m == 0 || m == 180) ? 1.0 : 2.0;
    Dt[(size_t)m * 360 + n]         = (float)(cm * c);   // cos rows
    Dt[(size_t)(181 + m) * 360 + n] = (float)(-cm * s);  // -sin rows
}

// wt[l][i][o] = W[o][i][l]   (W per-layer: o stride 46336, i stride 181, l stride 1)
__global__ __launch_bounds__(256) void transpose_wspec(const float* __restrict__ W, float* __restrict__ WT) {
    __shared__ float tile[32][33];
    int l0 = blockIdx.x * 32, o0 = blockIdx.y * 32, i = blockIdx.z;
    int c = threadIdx.x & 31, r = threadIdx.x >> 5;
#pragma unroll
    for (int j = 0; j < 4; j++) {
        int row = r + j * 8;
        float v = 0.f;
        if (l0 + c < 181) v = W[(size_t)(o0 + row) * 46336 + i * 181 + (l0 + c)];
        tile[row][c] = v;
    }
    __syncthreads();
#pragma unroll
    for (int j = 0; j < 4; j++) {
        int row = r + j * 8;
        if (l0 + row < 181) WT[(size_t)(l0 + row) * 65536 + i * 256 + (o0 + c)] = tile[c][row];
    }
}

// ---------------- LayerNorm over channel dim (256), per pixel ----------------
__global__ __launch_bounds__(256) void ln_kernel(const float* __restrict__ X, float* __restrict__ Y) {
    int p0 = blockIdx.x * 64;
    int t = threadIdx.x;
    int ps = t & 63, cg = t >> 6;
    int p = p0 + ps;
    bool ok = p < PIXg;
    float sum = 0.f, sumsq = 0.f;
    if (ok) {
        for (int c = cg; c < EMBg; c += 4) {
            float v = X[(size_t)c * PIXg + p];
            sum += v; sumsq += v * v;
        }
    }
    __shared__ float s1[4][64];
    __shared__ float s2[4][64];
    s1[cg][ps] = sum; s2[cg][ps] = sumsq;
    __syncthreads();
    float tot  = s1[0][ps] + s1[1][ps] + s1[2][ps] + s1[3][ps];
    float tot2 = s2[0][ps] + s2[1][ps] + s2[2][ps] + s2[3][ps];
    float mu = tot * (1.0f / 256.0f);
    float var = tot2 * (1.0f / 256.0f) - mu * mu;
    float inv = rsqrtf(var + 1e-6f);
    if (ok) {
        for (int c = cg; c < EMBg; c += 4) {
            size_t offp = (size_t)c * PIXg + p;
            Y[offp] = (X[offp] - mu) * inv;
        }
    }
}

// x1 = gelu(Y + S + bias[c]), float4 over [256][PIX]
__global__ __launch_bounds__(256) void add_bias_gelu(const float* __restrict__ Y, const float* __restrict__ S,
                                                     const float* __restrict__ bsp, float* __restrict__ O) {
    int idx = blockIdx.x * 256 + threadIdx.x;   // float4 index
    int c = idx / 16290;                        // PIX/4 = 16290
    float b = bsp[c];
    float4 y = reinterpret_cast<const float4*>(Y)[idx];
    float4 s = reinterpret_cast<const float4*>(S)[idx];
    float4 o;
    o.x = gelu_f(y.x + s.x + b);
    o.y = gelu_f(y.y + s.y + b);
    o.z = gelu_f(y.z + s.z + b);
    o.w = gelu_f(y.w + s.w + b);
    reinterpret_cast<float4*>(O)[idx] = o;
}

// ---------------- single-buffer strided batched fp32 GEMM ----------------
// C[z][i][j] = sum_k A[z][i][k]*B[z][k][j]; z in [0, Zin*planes); plane offset via *ps.
// epilogue: *zscale[z], +bias[i], +resid (C layout), gelu, +=C
// REGISTER-PRESSURE NOTE: round-2 (64 VGPR) and round-3 (128 VGPR) both spilled the
// 8x8 accumulator to scratch (5-12 GB HBM traffic/dispatch). This version returns to
// the round-1-proven footprint (~104 VGPR): single LDS buffer, NO cross-loop prefetch
// registers, NO precomputed address arrays. Do not re-add them without checking VGPRs.
__global__ __launch_bounds__(256, 2) void gemm_f32(
    const float* __restrict__ A, int Ars, int Acs, int Azs, int Aps,
    const float* __restrict__ B, int Brs, int Bcs, int Bzs, int Bps,
    float* __restrict__ C, int Crs, int Ccs, int Czs, int Cps,
    const float* __restrict__ bias, const float* __restrict__ zscale,
    const float* __restrict__ resid,
    int M, int N, int K, int Zin, int flags)
{
    int z = blockIdx.z;
    if (z >= Zin) { z -= Zin; A += Aps; B += Bps; C += Cps; if (resid) resid += Cps; }
    A += (size_t)z * Azs; B += (size_t)z * Bzs; C += (size_t)z * Czs;
    if (resid) resid += (size_t)z * Czs;

    const int bm = blockIdx.y * 128, bn = blockIdx.x * 128;
    const int t = threadIdx.x;
    const int tx = t & 15, ty = t >> 4;

    __shared__ float As[16][132];
    __shared__ float Bs[16][132];

    float acc[8][8];
#pragma unroll
    for (int i = 0; i < 8; i++)
#pragma unroll
        for (int j = 0; j < 8; j++) acc[i][j] = 0.0f;

    for (int k0 = 0; k0 < K; k0 += 16) {
        // ---- stage A tile ----
        if (Acs == 1) {
            int kk = t & 15, r = t >> 4;
            int gk = k0 + kk; bool kv = gk < K;
#pragma unroll
            for (int i = 0; i < 8; i++) {
                int gr = bm + r + i * 16; if (gr > M - 1) gr = M - 1;
                As[kk][r + i * 16] = kv ? A[(size_t)gr * Ars + gk] : 0.f;
            }
        } else {
            int row = t & 127, kb = t >> 7;
            int gr = bm + row; if (gr > M - 1) gr = M - 1;
            size_t base = (size_t)gr * Ars;
#pragma unroll
            for (int i = 0; i < 8; i++) {
                int gk = k0 + kb + i * 2;
                As[kb + i * 2][row] = (gk < K) ? A[base + (size_t)gk * Acs] : 0.f;
            }
        }
        // ---- stage B tile ----
        if (Bcs == 1) {
            int col = t & 127, kb = t >> 7;
            int gc = bn + col; if (gc > N - 1) gc = N - 1;
#pragma unroll
            for (int i = 0; i < 8; i++) {
                int gk = k0 + kb + i * 2;
                Bs[kb + i * 2][col] = (gk < K) ? B[(size_t)gk * Brs + gc] : 0.f;
            }
        } else {
            int kk = t & 15, cb = t >> 4;
            int gk = k0 + kk; bool kv = gk < K;
#pragma unroll
            for (int i = 0; i < 8; i++) {
                int gc = bn + cb + i * 16; if (gc > N - 1) gc = N - 1;
                Bs[kk][cb + i * 16] = kv ? B[(size_t)gk * Brs + (size_t)gc * Bcs] : 0.f;
            }
        }
        __syncthreads();
#pragma unroll
        for (int kk = 0; kk < 16; kk++) {
            float4 a0 = *(const float4*)&As[kk][ty * 4];
            float4 a1 = *(const float4*)&As[kk][ty * 4 + 64];
            float4 b0 = *(const float4*)&Bs[kk][tx * 4];
            float4 b1 = *(const float4*)&Bs[kk][tx * 4 + 64];
            float av[8] = {a0.x, a0.y, a0.z, a0.w, a1.x, a1.y, a1.z, a1.w};
            float bv[8] = {b0.x, b0.y, b0.z, b0.w, b1.x, b1.y, b1.z, b1.w};
#pragma unroll
            for (int i = 0; i < 8; i++)
#pragma unroll
                for (int j = 0; j < 8; j++)
                    acc[i][j] = fmaf(av[i], bv[j], acc[i][j]);
        }
        __syncthreads();
    }

    const float zs = zscale ? zscale[z] : 1.0f;
    const bool fastN = (Ccs == 1) && (bn + 128 <= N);
#pragma unroll
    for (int i = 0; i < 8; i++) {
        int gi = bm + ty * 4 + (i & 3) + ((i >> 2) << 6);
        if (gi >= M) continue;
        float bval = bias ? bias[gi] : 0.0f;
        size_t crow = (size_t)gi * (size_t)Crs;
        if (fastN) {
#pragma unroll
            for (int h = 0; h < 2; h++) {
                int gj = bn + tx * 4 + h * 64;
                size_t off = crow + (size_t)gj;
                float4 v;
                v.x = acc[i][h * 4 + 0] * zs + bval;
                v.y = acc[i][h * 4 + 1] * zs + bval;
                v.z = acc[i][h * 4 + 2] * zs + bval;
                v.w = acc[i][h * 4 + 3] * zs + bval;
                if (resid) { float4 r = *(const float4*)&resid[off];
                             v.x += r.x; v.y += r.y; v.z += r.z; v.w += r.w; }
                if (flags & FLAG_GELU) { v.x = gelu_f(v.x); v.y = gelu_f(v.y);
                                         v.z = gelu_f(v.z); v.w = gelu_f(v.w); }
                if (flags & FLAG_ACC)  { float4 c0 = *(const float4*)&C[off];
                                         v.x += c0.x; v.y += c0.y; v.z += c0.z; v.w += c0.w; }
                *(float4*)&C[off] = v;
            }
        } else {
#pragma unroll
            for (int j = 0; j < 8; j++) {
                int gj = bn + tx * 4 + (j & 3) + ((j >> 2) << 6);
                if (gj >= N) continue;
                size_t off = crow + (size_t)gj * (size_t)Ccs;
                float v = acc[i][j] * zs + bval;
                if (resid) v += resid[off];
                if (flags & FLAG_GELU) v = gelu_f(v);
                if (flags & FLAG_ACC) v += C[off];
                C[off] = v;
            }
        }
    }
}

static inline void launch_gemm(hipStream_t s,
    const float* A, int Ars, int Acs, int Azs, int Aps,
    const float* B, int Brs, int Bcs, int Bzs, int Bps,
    float* C, int Crs, int Ccs, int Czs, int Cps,
    const float* bias, const float* zscale, const float* resid,
    int M, int N, int K, int Zin, int nplanes, int flags)
{
    dim3 grid((N + 127) / 128, (M + 127) / 128, Zin * nplanes);
    hipLaunchKernelGGL(gemm_f32, grid, dim3(256), 0, s,
                       A, Ars, Acs, Azs, Aps, B, Brs, Bcs, Bzs, Bps,
                       C, Crs, Ccs, Czs, Cps, bias, zscale, resid,
                       M, N, K, Zin, flags);
}

extern "C" void kernel_launch(void* const* d_in, const int* in_sizes, int n_in,
                              void* d_out, int out_size, void* d_ws, size_t ws_size,
                              hipStream_t stream)
{
    const float* x      = (const float*)d_in[0];
    const float* w_enc  = (const float*)d_in[1];
    const float* b_enc  = (const float*)d_in[2];
    const float* pos    = (const float*)d_in[3];
    const float* w_spec = (const float*)d_in[4];
    const float* b_spec = (const float*)d_in[5];
    const float* w_is   = (const float*)d_in[6];
    const float* b_is   = (const float*)d_in[7];
    const float* w_f1   = (const float*)d_in[8];
    const float* b_f1   = (const float*)d_in[9];
    const float* w_f2   = (const float*)d_in[10];
    const float* b_f2   = (const float*)d_in[11];
    const float* w_dec  = (const float*)d_in[12];
    const float* b_dec  = (const float*)d_in[13];
    float* out = (float*)d_out;
    float* ws  = (float*)d_ws;

    size_t off = 0;
    auto alloc = [&](size_t n) { size_t o = off; off += (n + 63) & ~(size_t)63; return o; };
    float* P     = ws + alloc((size_t)181 * 181 * 181);
    float* Etrig = ws + alloc((size_t)2 * PIXg);
    float* Dt    = ws + alloc((size_t)362 * 360);
    float* wqs   = ws + alloc(181);
    float* S0    = ws + alloc((size_t)2 * PLANEg);
    float* S1    = ws + alloc((size_t)2 * PLANEg);   // contiguous after S0
    float* hbuf  = ws + alloc((size_t)EMBg * PIXg);
    float* xn    = ws + alloc((size_t)EMBg * PIXg);
    float* tA    = ws + alloc((size_t)EMBg * PIXg);  // wt scratch, then y, then x1
    float* tB    = ws + alloc((size_t)EMBg * PIXg);
    float* hmlp  = S0;   // 512*PIX floats spans S0..S1 (spectral bufs dead by MLP time)

    init_legendre<<<(181 * 181 + 255) / 256, 256, 0, stream>>>(P);
    init_trig<<<(181 * 360 + 255) / 256, 256, 0, stream>>>(Etrig, Dt, wqs);

    // encoder: h = w_enc*x + b_enc + pos_emb
    launch_gemm(stream, w_enc, 26, 1, 0, 0,  x, PIXg, 1, 0, 0,  hbuf, PIXg, 1, 0, 0,
                b_enc, nullptr, pos, EMBg, PIXg, 26, 1, 1, 0);

    for (int L = 0; L < 4; ++L) {
        const float* wsp = w_spec + (size_t)L * EMBg * EMBg * 181;
        const float* bsp = b_spec + (size_t)L * EMBg;
        const float* wis = w_is   + (size_t)L * EMBg * EMBg;
        const float* bis = b_is   + (size_t)L * EMBg;
        const float* wf1 = w_f1   + (size_t)L * MHIDg * EMBg;
        const float* bf1 = b_f1   + (size_t)L * MHIDg;
        const float* wf2 = w_f2   + (size_t)L * EMBg * MHIDg;
        const float* bf2 = b_f2   + (size_t)L * EMBg;

        // wt[l][i][o] = wsp[o][i][l]  (into tA scratch; dead until iDFT output)
        transpose_wspec<<<dim3(6, 8, 256), 256, 0, stream>>>(wsp, tA);

        // xn = LN(h)
        ln_kernel<<<1019, 256, 0, stream>>>(hbuf, xn);

        // DFT (z=k, planes cos/sin): F[pl][k][m][c] = sum_n E[pl][m][n]*xn[c][k*360+n], *wqs[k]
        launch_gemm(stream, Etrig, 360, 1, 0, PIXg,  xn, 1, PIXg, 360, 0,
                    S0, 256, 1, 46336, PLANEg,
                    nullptr, wqs, nullptr, 181, 256, 360, 181, 2, 0);
        // Legendre analysis (z=m): coeff[pl][m][l][c] = sum_k P[l][m][k]*F[pl][k][m][c]
        launch_gemm(stream, P, LDIMg, 1, 181, 0,  S0, 46336, 1, 256, PLANEg,
                    S1, 256, 1, 46336, PLANEg,
                    nullptr, nullptr, nullptr, 181, 256, 181, 181, 2, 0);
        // dhconv (z=l): co[pl][m][l][o] = sum_i coeff[pl][m][l][i]*wt[l][i][o]
        launch_gemm(stream, S1, 46336, 1, 256, PLANEg,  tA, 256, 1, 65536, 0,
                    S0, 46336, 1, 256, PLANEg,
                    nullptr, nullptr, nullptr, 181, 256, 256, 181, 2, 0);
        // Legendre synthesis (z=m): Fo[pl][m][k][c] = sum_l P[l][m][k]*co[pl][m][l][c]
        launch_gemm(stream, P, 1, LDIMg, 181, 0,  S0, 256, 1, 46336, PLANEg,
                    S1, 256, 1, 46336, PLANEg,
                    nullptr, nullptr, nullptr, 181, 256, 181, 181, 2, 0);
        // iDFT (z=k): y[c][k*360+n] = sum_{m'=0..361} Fo[m'][k][c]*Dt[m'][n]
        // (re plane m'=0..180 and im plane m'=181..361 are contiguous: 181*46336 == PLANEg)
        launch_gemm(stream, S1, 1, 46336, 256, 0,  Dt, 360, 1, 0, 0,
                    tA, PIXg, 1, 360, 0,
                    nullptr, nullptr, nullptr, 256, 360, 362, 181, 1, 0);
        // inner skip: S = wis*xn + bis -> tB
        launch_gemm(stream, wis, 256, 1, 0, 0,  xn, PIXg, 1, 0, 0,  tB, PIXg, 1, 0, 0,
                    bis, nullptr, nullptr, 256, PIXg, 256, 1, 1, 0);
        // x1 = gelu(y + b_spec + S) -> tA
        add_bias_gelu<<<16290, 256, 0, stream>>>(tA, tB, bsp, tA);
        // x2 = LN(x1) -> tB
        ln_kernel<<<1019, 256, 0, stream>>>(tA, tB);
        // MLP fc1: hmlp = gelu(wf1*x2 + bf1)
        launch_gemm(stream, wf1, 256, 1, 0, 0,  tB, PIXg, 1, 0, 0,  hmlp, PIXg, 1, 0, 0,
                    bf1, nullptr, nullptr, MHIDg, PIXg, 256, 1, 1, FLAG_GELU);
        // MLP fc2 + residual xn -> h
        launch_gemm(stream, wf2, 512, 1, 0, 0,  hmlp, PIXg, 1, 0, 0,  hbuf, PIXg, 1, 0, 0,
                    bf2, nullptr, xn, EMBg, PIXg, 512, 1, 1, 0);
    }

    // decoder: out = w_dec[:, :256]*h + w_dec[:, 256:]*x + b_dec
    launch_gemm(stream, w_dec, 282, 1, 0, 0,  hbuf, PIXg, 1, 0, 0,  out, PIXg, 1, 0, 0,
                b_dec, nullptr, nullptr, 26, PIXg, 256, 1, 1, 0);
    launch_gemm(stream, w_dec + 256, 282, 1, 0, 0,  x, PIXg, 1, 0, 0,  out, PIXg, 1, 0, 0,
                nullptr, nullptr, nullptr, 26, PIXg, 26, 1, 1, FLAG_ACC);
}